// Round 2
// baseline (1756.989 us; speedup 1.0000x reference)
//
#include <hip/hip_runtime.h>
#include <stdint.h>

#define NTOK 128
#define DHID 256
#define NHEAD 4
#define DHEAD 64

typedef short bf16x8 __attribute__((ext_vector_type(8)));
typedef float f32x4 __attribute__((ext_vector_type(4)));

#define MFMA(a,b,c) __builtin_amdgcn_mfma_f32_16x16x32_bf16((a),(b),(c),0,0,0)

__device__ __forceinline__ float bf2f(uint16_t u){
  union { uint32_t i; float f; } v; v.i = ((uint32_t)u) << 16; return v.f;
}
__device__ __forceinline__ uint16_t f2bf(float f){
  union { uint32_t i; float f; } v; v.f = f;
  uint32_t i = v.i + 0x7FFFu + ((v.i >> 16) & 1u);
  return (uint16_t)(i >> 16);
}

// ---------------- dtype probe: low half-word exponent-field statistics ----------------
__global__ void k_detect(const uint32_t* __restrict__ raw, uint32_t* __restrict__ flag){
  int lane = threadIdx.x;           // 64 threads, 1 block
  int hits = 0;
  #pragma unroll
  for (int i = 0; i < 16; i++){
    uint32_t w = raw[lane*16 + i];
    uint32_t e = (w >> 7) & 0xFFu;  // exponent field of LOW 16 bits viewed as bf16
    hits += (e >= 0x70u && e <= 0x8Fu) ? 1 : 0;
  }
  #pragma unroll
  for (int m = 1; m < 64; m <<= 1) hits += __shfl_xor(hits, m);
  if (lane == 0) *flag = (hits > 512) ? 1u : 0u;   // 1 = bf16, 0 = fp32
}

// ---------------- normalize any float tensor to bf16 ----------------
__global__ void k_conv(const void* __restrict__ src, unsigned long long off,
                       uint16_t* __restrict__ dst, const uint32_t* __restrict__ flag, int n){
  const int isbf = (int)*flag;
  int i0 = (blockIdx.x * blockDim.x + threadIdx.x) * 8;
  int stride = gridDim.x * blockDim.x * 8;
  if (isbf){
    const uint16_t* s = (const uint16_t*)src + off;
    for (int i = i0; i < n; i += stride)
      *(bf16x8*)(dst + i) = *(const bf16x8*)(s + i);
  } else {
    const float* s = (const float*)src + off;
    for (int i = i0; i < n; i += stride){
      float4 a = *(const float4*)(s + i);
      float4 b = *(const float4*)(s + i + 4);
      uint16_t o[8] = {f2bf(a.x),f2bf(a.y),f2bf(a.z),f2bf(a.w),
                       f2bf(b.x),f2bf(b.y),f2bf(b.z),f2bf(b.w)};
      *(bf16x8*)(dst + i) = *(const bf16x8*)o;
    }
  }
}

// ---------------- store bf16 result to d_out in its native dtype ----------------
__global__ void k_store(const uint16_t* __restrict__ L, void* __restrict__ dst,
                        unsigned long long off, const uint32_t* __restrict__ flag, int n){
  const int isbf = (int)*flag;
  int i0 = (blockIdx.x * blockDim.x + threadIdx.x) * 8;
  int stride = gridDim.x * blockDim.x * 8;
  if (isbf){
    uint16_t* d = (uint16_t*)dst + off;
    for (int i = i0; i < n; i += stride)
      *(bf16x8*)(d + i) = *(const bf16x8*)(L + i);
  } else {
    float* d = (float*)dst + off;
    for (int i = i0; i < n; i += stride){
      bf16x8 v = *(const bf16x8*)(L + i);
      #pragma unroll
      for (int e = 0; e < 8; e++) d[i + e] = bf2f((uint16_t)v[e]);
    }
  }
}

// ---------------- K0: pack mask rows into bitmasks + update flag ----------------
__global__ __launch_bounds__(256) void k_maskpack(const int* __restrict__ mask,
                                                  unsigned long long* __restrict__ packed,
                                                  unsigned char* __restrict__ upd, int nrows){
  int row = blockIdx.x * 4 + (threadIdx.x >> 6);
  if (row >= nrows) return;
  int lane = threadIdx.x & 63;
  const int* mrow = mask + (size_t)row * NTOK;
  unsigned long long b0 = __ballot(mrow[lane] != 0);
  unsigned long long b1 = __ballot(mrow[lane + 64] != 0);
  if (lane == 0){
    packed[row*2 + 0] = b0;
    packed[row*2 + 1] = b1;
    upd[row] = (unsigned char)((__popcll(b0) + __popcll(b1)) > 1 ? 1 : 0);
  }
}

// ---------------- K1: O[r, c0+c] = X[r,:256] @ W[c0+c,:256]^T + bias ----------------
__global__ __launch_bounds__(256) void k_qkv(
    const uint16_t* __restrict__ X,
    const uint16_t* __restrict__ Wq, const uint16_t* __restrict__ bq,
    const uint16_t* __restrict__ Wk, const uint16_t* __restrict__ bk,
    const uint16_t* __restrict__ Wv, const uint16_t* __restrict__ bv,
    uint16_t* __restrict__ Oq, uint16_t* __restrict__ Ok, uint16_t* __restrict__ Ov)
{
  extern __shared__ uint16_t sm[];
  uint16_t* As = sm;            // [64][256] XOR-swizzled 16B granules
  uint16_t* Bs = sm + 64*256;   // [64][256]
  const uint16_t* W; const uint16_t* bias; uint16_t* O;
  if (blockIdx.z == 0)      { W = Wq; bias = bq; O = Oq; }
  else if (blockIdx.z == 1) { W = Wk; bias = bk; O = Ok; }
  else                      { W = Wv; bias = bv; O = Ov; }
  const int r0 = blockIdx.y * 64;
  const int c0 = blockIdx.x * 64;
  const int tid = threadIdx.x;
  const int lane = tid & 63, lr = lane & 15, lg = lane >> 4;
  const int wav = tid >> 6;
  const int wr = (wav >> 1) * 32, wc = (wav & 1) * 32;

  #pragma unroll
  for (int i = 0; i < 8; i++){
    int c = tid + i*256;
    int row = c >> 5, g = c & 31;
    int gs = (g ^ (row & 7)) * 8;
    *(bf16x8*)(As + row*256 + gs) = *(const bf16x8*)(X + (size_t)(r0+row)*DHID + g*8);
    *(bf16x8*)(Bs + row*256 + gs) = *(const bf16x8*)(W + (size_t)(c0+row)*DHID + g*8);
  }
  __syncthreads();

  f32x4 acc[2][2] = {};
  #pragma unroll
  for (int kk = 0; kk < 8; kk++){
    int off = ((kk*4 + lg) ^ (lr & 7)) * 8;
    bf16x8 a0 = *(const bf16x8*)(As + (wr +      lr)*256 + off);
    bf16x8 a1 = *(const bf16x8*)(As + (wr + 16 + lr)*256 + off);
    bf16x8 b0 = *(const bf16x8*)(Bs + (wc +      lr)*256 + off);
    bf16x8 b1 = *(const bf16x8*)(Bs + (wc + 16 + lr)*256 + off);
    acc[0][0] = MFMA(a0, b0, acc[0][0]);
    acc[0][1] = MFMA(a0, b1, acc[0][1]);
    acc[1][0] = MFMA(a1, b0, acc[1][0]);
    acc[1][1] = MFMA(a1, b1, acc[1][1]);
  }
  #pragma unroll
  for (int i = 0; i < 2; i++)
  #pragma unroll
  for (int j = 0; j < 2; j++){
    int col = c0 + wc + j*16 + lr;
    float bvv = bf2f(bias[col]);
    #pragma unroll
    for (int rr = 0; rr < 4; rr++){
      int row = r0 + wr + i*16 + lg*4 + rr;
      O[(size_t)row*DHID + col] = f2bf(acc[i][j][rr] + bvv);
    }
  }
}

// ---------------- K2: fused attention per (b,h) ----------------
__global__ __launch_bounds__(256) void k_attn(
    const uint16_t* __restrict__ Q, const uint16_t* __restrict__ Kb, const uint16_t* __restrict__ V,
    const unsigned long long* __restrict__ packed, uint16_t* __restrict__ ctx)
{
  extern __shared__ uint16_t sm[];
  uint16_t* Ks = sm;              // [128][64]  swizzled
  uint16_t* Vt = sm + 128*64;     // [64][128]  V transposed, swizzled
  uint16_t* Ps = Vt + 64*128;     // [128][128] P, swizzled
  const int b = blockIdx.x >> 2;
  const int h = blockIdx.x & 3;
  const int tid = threadIdx.x, lane = tid & 63, wav = tid >> 6;
  const int lr = lane & 15, lg = lane >> 4;
  const size_t base = ((size_t)b * NTOK) * DHID + h * DHEAD;

  #pragma unroll
  for (int i = 0; i < 4; i++){            // K tile -> LDS (coalesced)
    int c = tid + i*256;
    int row = c >> 3, g = c & 7;
    *(bf16x8*)(Ks + row*64 + (g ^ (row & 7))*8) =
        *(const bf16x8*)(Kb + base + (size_t)row*DHID + g*8);
  }
  #pragma unroll
  for (int i = 0; i < 4; i++){            // V tile -> LDS transposed
    int c = tid + i*256;
    int n = c & 127, d8 = (c >> 7) * 8;
    bf16x8 v = *(const bf16x8*)(V + base + (size_t)n*DHID + d8);
    #pragma unroll
    for (int e = 0; e < 8; e++){
      int d = d8 + e;
      Vt[d*128 + ((n >> 3) ^ (d & 7))*8 + (n & 7)] = (uint16_t)v[e];
    }
  }
  __syncthreads();

  const int qrow0 = wav * 32;
  bf16x8 qf[2][2];
  #pragma unroll
  for (int i = 0; i < 2; i++)
  #pragma unroll
  for (int kk = 0; kk < 2; kk++)
    qf[i][kk] = *(const bf16x8*)(Q + base + (size_t)(qrow0 + i*16 + lr)*DHID + kk*32 + lg*8);

  f32x4 sa[2][8] = {};
  #pragma unroll
  for (int kk = 0; kk < 2; kk++){
    int off = ((kk*4 + lg) ^ (lr & 7)) * 8;
    #pragma unroll
    for (int j = 0; j < 8; j++){
      bf16x8 bf = *(const bf16x8*)(Ks + (j*16 + lr)*64 + off);
      sa[0][j] = MFMA(qf[0][kk], bf, sa[0][j]);
      sa[1][j] = MFMA(qf[1][kk], bf, sa[1][j]);
    }
  }
  #pragma unroll
  for (int i = 0; i < 2; i++){
    #pragma unroll
    for (int rr = 0; rr < 4; rr++){
      int n = qrow0 + i*16 + lg*4 + rr;
      unsigned long long m0 = packed[((size_t)b*NTOK + n)*2 + 0];
      unsigned long long m1 = packed[((size_t)b*NTOK + n)*2 + 1];
      float sv[8];
      float mx = -3.0e38f;
      #pragma unroll
      for (int j = 0; j < 8; j++){
        int col = j*16 + lr;
        unsigned long long w = (col < 64) ? m0 : m1;
        float s = sa[i][j][rr] * 0.125f;
        sv[j] = ((w >> (col & 63)) & 1ull) ? s : -1e9f;
        mx = fmaxf(mx, sv[j]);
      }
      mx = fmaxf(mx, __shfl_xor(mx, 1));
      mx = fmaxf(mx, __shfl_xor(mx, 2));
      mx = fmaxf(mx, __shfl_xor(mx, 4));
      mx = fmaxf(mx, __shfl_xor(mx, 8));
      float sum = 0.f;
      #pragma unroll
      for (int j = 0; j < 8; j++){ sv[j] = __expf(sv[j] - mx); sum += sv[j]; }
      sum += __shfl_xor(sum, 1);
      sum += __shfl_xor(sum, 2);
      sum += __shfl_xor(sum, 4);
      sum += __shfl_xor(sum, 8);
      float inv = 1.f / sum;
      #pragma unroll
      for (int j = 0; j < 8; j++){
        int col = j*16 + lr;
        Ps[n*128 + ((col >> 3) ^ (n & 7))*8 + (col & 7)] = f2bf(sv[j] * inv);
      }
    }
  }
  __syncthreads();

  f32x4 oa[2][4] = {};
  #pragma unroll
  for (int kk = 0; kk < 4; kk++){
    int off = ((kk*4 + lg) ^ (lr & 7)) * 8;
    bf16x8 a0 = *(const bf16x8*)(Ps + (qrow0 +      lr)*128 + off);
    bf16x8 a1 = *(const bf16x8*)(Ps + (qrow0 + 16 + lr)*128 + off);
    #pragma unroll
    for (int j = 0; j < 4; j++){
      bf16x8 bf = *(const bf16x8*)(Vt + (j*16 + lr)*128 + off);
      oa[0][j] = MFMA(a0, bf, oa[0][j]);
      oa[1][j] = MFMA(a1, bf, oa[1][j]);
    }
  }
  #pragma unroll
  for (int i = 0; i < 2; i++)
  #pragma unroll
  for (int j = 0; j < 4; j++)
  #pragma unroll
  for (int rr = 0; rr < 4; rr++){
    int n = qrow0 + i*16 + lg*4 + rr;
    ctx[((size_t)b*NTOK + n)*DHID + h*DHEAD + j*16 + lr] = f2bf(oa[i][j][rr]);
  }
}

// ---------------- K3: info = ctx@Wo^T ; gi = info@Wih^T ; gh = h@Whh^T ; GRU ----------------
__global__ __launch_bounds__(256) void k_gru(
    const uint16_t* __restrict__ ctxp, const uint16_t* __restrict__ lat_in,
    const uint16_t* __restrict__ Wo, const uint16_t* __restrict__ Wih, const uint16_t* __restrict__ Whh,
    const uint16_t* __restrict__ bih, const uint16_t* __restrict__ bhh,
    const unsigned char* __restrict__ upd, uint16_t* __restrict__ lat_out)
{
  extern __shared__ uint16_t sm[];
  uint16_t* Cs = sm;            // [64][256] ctx (later reused as info [64][64])
  uint16_t* Ls = sm + 64*256;   // [64][256] latent
  const int r0 = blockIdx.x * 64;
  const int tid = threadIdx.x, lane = tid & 63, wav = tid >> 6;
  const int lr = lane & 15, lg = lane >> 4;

  #pragma unroll
  for (int i = 0; i < 8; i++){
    int c = tid + i*256;
    int row = c >> 5, g = c & 31;
    int gs = (g ^ (row & 7)) * 8;
    *(bf16x8*)(Cs + row*256 + gs) = *(const bf16x8*)(ctxp  + (size_t)(r0+row)*DHID + g*8);
    *(bf16x8*)(Ls + row*256 + gs) = *(const bf16x8*)(lat_in + (size_t)(r0+row)*DHID + g*8);
  }
  __syncthreads();

  f32x4 ai[4] = {};
  #pragma unroll
  for (int kk = 0; kk < 8; kk++){
    int off = ((kk*4 + lg) ^ (lr & 7)) * 8;
    bf16x8 a = *(const bf16x8*)(Cs + (wav*16 + lr)*256 + off);
    #pragma unroll
    for (int j = 0; j < 4; j++){
      bf16x8 b = *(const bf16x8*)(Wo + (size_t)(j*16 + lr)*DHID + kk*32 + lg*8);
      ai[j] = MFMA(a, b, ai[j]);
    }
  }
  __syncthreads();
  uint16_t* Is = Cs;               // reuse as info [64][64] swizzled
  #pragma unroll
  for (int j = 0; j < 4; j++)
  #pragma unroll
  for (int rr = 0; rr < 4; rr++){
    int row = wav*16 + lg*4 + rr;
    int col = j*16 + lr;
    Is[row*64 + ((col >> 3) ^ (row & 7))*8 + (col & 7)] = f2bf(ai[j][rr]);
  }
  __syncthreads();

  const int wrow = wav*16;
  for (int cs = 0; cs < 16; cs++){
    int c0 = cs*16;
    f32x4 gi[3] = {}; f32x4 gh[3] = {};
    #pragma unroll
    for (int kk = 0; kk < 2; kk++){
      int off = ((kk*4 + lg) ^ (lr & 7)) * 8;
      bf16x8 a = *(const bf16x8*)(Is + (wrow + lr)*64 + off);
      #pragma unroll
      for (int g = 0; g < 3; g++){
        bf16x8 b = *(const bf16x8*)(Wih + (size_t)(g*256 + c0 + lr)*DHEAD + kk*32 + lg*8);
        gi[g] = MFMA(a, b, gi[g]);
      }
    }
    #pragma unroll
    for (int kk = 0; kk < 8; kk++){
      int off = ((kk*4 + lg) ^ (lr & 7)) * 8;
      bf16x8 a = *(const bf16x8*)(Ls + (wrow + lr)*256 + off);
      #pragma unroll
      for (int g = 0; g < 3; g++){
        bf16x8 b = *(const bf16x8*)(Whh + (size_t)(g*256 + c0 + lr)*DHID + kk*32 + lg*8);
        gh[g] = MFMA(a, b, gh[g]);
      }
    }
    int col = c0 + lr;
    float bir = bf2f(bih[col]), biz = bf2f(bih[256+col]), bin_ = bf2f(bih[512+col]);
    float bhr = bf2f(bhh[col]), bhz = bf2f(bhh[256+col]), bhn = bf2f(bhh[512+col]);
    #pragma unroll
    for (int rr = 0; rr < 4; rr++){
      int row = wrow + lg*4 + rr;
      int gcol = (col >> 3) ^ (row & 7);
      float hv = bf2f(Ls[row*256 + gcol*8 + (col & 7)]);
      float rg = 1.f / (1.f + __expf(-((gi[0][rr]+bir) + (gh[0][rr]+bhr))));
      float zg = 1.f / (1.f + __expf(-((gi[1][rr]+biz) + (gh[1][rr]+bhz))));
      float ng = tanhf((gi[2][rr]+bin_) + rg*(gh[2][rr]+bhn));
      float hp = (1.f - zg)*ng + zg*hv;
      float ov = upd[r0+row] ? hp : hv;
      lat_out[(size_t)(r0+row)*DHID + col] = f2bf(ov);
    }
  }
}

extern "C" void kernel_launch(void* const* d_in, const int* in_sizes, int n_in,
                              void* d_out, int out_size, void* d_ws, size_t ws_size,
                              hipStream_t stream)
{
  (void)in_sizes; (void)n_in; (void)out_size;
  const void* latent = d_in[0];
  const int*  mask   = (const int*)d_in[1];
  const void* Wq  = d_in[3]; const void* bq  = d_in[4];
  const void* Wk  = d_in[5]; const void* bk  = d_in[6];
  const void* Wv  = d_in[7]; const void* bv  = d_in[8];
  const void* Wo  = d_in[9];
  const void* Wih = d_in[10]; const void* Whh = d_in[11];
  const void* bih = d_in[12]; const void* bhh = d_in[13];

  // ---- workspace carve: flag + bf16 weight copies + per-chunk region ----
  uint8_t* p = (uint8_t*)d_ws;
  uint32_t* flag = (uint32_t*)p;            p += 256;
  uint16_t* Wqc  = (uint16_t*)p;            p += 65536*2;
  uint16_t* Wkc  = (uint16_t*)p;            p += 65536*2;
  uint16_t* Wvc  = (uint16_t*)p;            p += 65536*2;
  uint16_t* Woc  = (uint16_t*)p;            p += 16384*2;
  uint16_t* Wihc = (uint16_t*)p;            p += 49152*2;
  uint16_t* Whhc = (uint16_t*)p;            p += 196608*2;
  uint16_t* bqc  = (uint16_t*)p;            p += 512;
  uint16_t* bkc  = (uint16_t*)p;            p += 512;
  uint16_t* bvc  = (uint16_t*)p;            p += 512;
  uint16_t* bihc = (uint16_t*)p;            p += 1536;
  uint16_t* bhhc = (uint16_t*)p;            p += 1536;
  uint8_t* chunk0 = p;
  size_t reserved = (size_t)(chunk0 - (uint8_t*)d_ws);
  const size_t perb = 5ull*65536 + 2048 + 128;   // L, q, k, v, ctx (bf16) + packed + upd

  const int Btot = 1024;
  int CB = (int)((ws_size > reserved ? ws_size - reserved : 0) / perb);
  if (CB > Btot) CB = Btot;
  if (CB < 1)    CB = 1;

  auto cgrid = [](int n){ int b = (n/8 + 255)/256; if (b > 2048) b = 2048; if (b < 1) b = 1; return (unsigned)b; };

  k_detect<<<1, 64, 0, stream>>>((const uint32_t*)latent, flag);
  k_conv<<<cgrid(65536), 256, 0, stream>>>(Wq, 0, Wqc, flag, 65536);
  k_conv<<<cgrid(65536), 256, 0, stream>>>(Wk, 0, Wkc, flag, 65536);
  k_conv<<<cgrid(65536), 256, 0, stream>>>(Wv, 0, Wvc, flag, 65536);
  k_conv<<<cgrid(16384), 256, 0, stream>>>(Wo, 0, Woc, flag, 16384);
  k_conv<<<cgrid(49152), 256, 0, stream>>>(Wih, 0, Wihc, flag, 49152);
  k_conv<<<cgrid(196608),256, 0, stream>>>(Whh, 0, Whhc, flag, 196608);
  k_conv<<<1, 256, 0, stream>>>(bq, 0, bqc, flag, 256);
  k_conv<<<1, 256, 0, stream>>>(bk, 0, bkc, flag, 256);
  k_conv<<<1, 256, 0, stream>>>(bv, 0, bvc, flag, 256);
  k_conv<<<1, 256, 0, stream>>>(bih, 0, bihc, flag, 768);
  k_conv<<<1, 256, 0, stream>>>(bhh, 0, bhhc, flag, 768);

  for (int b0 = 0; b0 < Btot; b0 += CB){
    int cb = (Btot - b0 < CB) ? (Btot - b0) : CB;
    int rows = cb * 128;
    int nelem = rows * DHID;
    uint8_t* q = chunk0;
    uint16_t* L    = (uint16_t*)q; q += (size_t)cb*65536;
    uint16_t* q_ws = (uint16_t*)q; q += (size_t)cb*65536;
    uint16_t* k_ws = (uint16_t*)q; q += (size_t)cb*65536;
    uint16_t* v_ws = (uint16_t*)q; q += (size_t)cb*65536;
    uint16_t* c_ws = (uint16_t*)q; q += (size_t)cb*65536;
    unsigned long long* packed = (unsigned long long*)q; q += (size_t)cb*2048;
    unsigned char* updp = (unsigned char*)q;

    k_conv<<<cgrid(nelem), 256, 0, stream>>>(latent, (unsigned long long)b0*NTOK*DHID, L, flag, nelem);
    k_maskpack<<<dim3(rows/4), 256, 0, stream>>>(mask + (size_t)b0*NTOK*NTOK, packed, updp, rows);

    for (int layer = 0; layer < 2; layer++){
      k_qkv <<<dim3(4, rows/64, 3), 256, 65536, stream>>>(L, Wqc,bqc, Wkc,bkc, Wvc,bvc, q_ws, k_ws, v_ws);
      k_attn<<<dim3(cb*NHEAD),      256, 65536, stream>>>(q_ws, k_ws, v_ws, packed, c_ws);
      k_gru <<<dim3(rows/64),       256, 65536, stream>>>(c_ws, L, Woc, Wihc, Whhc, bihc, bhhc, updp, L);
    }
    k_store<<<cgrid(nelem), 256, 0, stream>>>(L, d_out, (unsigned long long)b0*NTOK*DHID, flag, nelem);
  }
}

// Round 3
// 853.771 us; speedup vs baseline: 2.0579x; 2.0579x over previous
//
#include <hip/hip_runtime.h>
#include <stdint.h>

#define NTOK 128
#define DHID 256
#define NHEAD 4
#define DHEAD 64

typedef short bf16x8 __attribute__((ext_vector_type(8)));
typedef float f32x4 __attribute__((ext_vector_type(4)));

#define MFMA(a,b,c) __builtin_amdgcn_mfma_f32_16x16x32_bf16((a),(b),(c),0,0,0)

__device__ __forceinline__ float bf2f(uint16_t u){
  union { uint32_t i; float f; } v; v.i = ((uint32_t)u) << 16; return v.f;
}
__device__ __forceinline__ uint16_t f2bf(float f){
  union { uint32_t i; float f; } v; v.f = f;
  uint32_t i = v.i + 0x7FFFu + ((v.i >> 16) & 1u);
  return (uint16_t)(i >> 16);
}

// ---------------- dtype probe ----------------
__global__ void k_detect(const uint32_t* __restrict__ raw, uint32_t* __restrict__ flag){
  int lane = threadIdx.x;
  int hits = 0;
  #pragma unroll
  for (int i = 0; i < 16; i++){
    uint32_t w = raw[lane*16 + i];
    uint32_t e = (w >> 7) & 0xFFu;
    hits += (e >= 0x70u && e <= 0x8Fu) ? 1 : 0;
  }
  #pragma unroll
  for (int m = 1; m < 64; m <<= 1) hits += __shfl_xor(hits, m);
  if (lane == 0) *flag = (hits > 512) ? 1u : 0u;   // 1 = bf16, 0 = fp32
}

// ---------------- normalize float tensor to bf16 ----------------
__global__ void k_conv(const void* __restrict__ src, unsigned long long off,
                       uint16_t* __restrict__ dst, const uint32_t* __restrict__ flag, int n){
  const int isbf = (int)*flag;
  int i0 = (blockIdx.x * blockDim.x + threadIdx.x) * 8;
  int stride = gridDim.x * blockDim.x * 8;
  if (isbf){
    const uint16_t* s = (const uint16_t*)src + off;
    for (int i = i0; i < n; i += stride)
      *(bf16x8*)(dst + i) = *(const bf16x8*)(s + i);
  } else {
    const float* s = (const float*)src + off;
    for (int i = i0; i < n; i += stride){
      float4 a = *(const float4*)(s + i);
      float4 b = *(const float4*)(s + i + 4);
      uint16_t o[8] = {f2bf(a.x),f2bf(a.y),f2bf(a.z),f2bf(a.w),
                       f2bf(b.x),f2bf(b.y),f2bf(b.z),f2bf(b.w)};
      *(bf16x8*)(dst + i) = *(const bf16x8*)o;
    }
  }
}

// ---------------- store result in native dtype ----------------
__global__ void k_store(const uint16_t* __restrict__ L, void* __restrict__ dst,
                        unsigned long long off, const uint32_t* __restrict__ flag, int n){
  const int isbf = (int)*flag;
  int i0 = (blockIdx.x * blockDim.x + threadIdx.x) * 8;
  int stride = gridDim.x * blockDim.x * 8;
  if (isbf){
    uint16_t* d = (uint16_t*)dst + off;
    for (int i = i0; i < n; i += stride)
      *(bf16x8*)(d + i) = *(const bf16x8*)(L + i);
  } else {
    float* d = (float*)dst + off;
    for (int i = i0; i < n; i += stride){
      bf16x8 v = *(const bf16x8*)(L + i);
      #pragma unroll
      for (int e = 0; e < 8; e++) d[i + e] = bf2f((uint16_t)v[e]);
    }
  }
}

// ---------------- K0: pack mask rows ----------------
__global__ __launch_bounds__(256) void k_maskpack(const int* __restrict__ mask,
                                                  unsigned long long* __restrict__ packed,
                                                  unsigned char* __restrict__ upd, int nrows){
  int row = blockIdx.x * 4 + (threadIdx.x >> 6);
  if (row >= nrows) return;
  int lane = threadIdx.x & 63;
  const int* mrow = mask + (size_t)row * NTOK;
  unsigned long long b0 = __ballot(mrow[lane] != 0);
  unsigned long long b1 = __ballot(mrow[lane + 64] != 0);
  if (lane == 0){
    packed[row*2 + 0] = b0;
    packed[row*2 + 1] = b1;
    upd[row] = (unsigned char)((__popcll(b0) + __popcll(b1)) > 1 ? 1 : 0);
  }
}

// ---------------- K1 v2: QKV — stage X once, loop 12 weight tiles ----------------
// grid: rows/64; block 256 = 4 waves (2x2 over 64x64 tile)
__global__ __launch_bounds__(256) void k_qkv(
    const uint16_t* __restrict__ X,
    const uint16_t* __restrict__ Wq, const uint16_t* __restrict__ bq,
    const uint16_t* __restrict__ Wk, const uint16_t* __restrict__ bk,
    const uint16_t* __restrict__ Wv, const uint16_t* __restrict__ bv,
    uint16_t* __restrict__ Oq, uint16_t* __restrict__ Ok, uint16_t* __restrict__ Ov)
{
  extern __shared__ uint16_t sm[];
  uint16_t* Xs = sm;            // [64][256] swizzled
  uint16_t* Ws = sm + 64*256;   // [64][256] swizzled (per weight tile)
  const int r0 = blockIdx.x * 64;
  const int tid = threadIdx.x;
  const int lane = tid & 63, lr = lane & 15, lg = lane >> 4;
  const int wav = tid >> 6;
  const int wr = (wav >> 1) * 32, wc = (wav & 1) * 32;

  #pragma unroll
  for (int i = 0; i < 8; i++){
    int c = tid + i*256, row = c >> 5, g = c & 31;
    *(bf16x8*)(Xs + row*256 + (g ^ (row & 7))*8) =
        *(const bf16x8*)(X + (size_t)(r0+row)*DHID + g*8);
  }

  bf16x8 wreg[8];
  auto wptr = [&](int t)->const uint16_t*{
    int w = t >> 2;
    return (w == 0) ? Wq : ((w == 1) ? Wk : Wv);
  };
  auto preload = [&](int t){
    const uint16_t* W = wptr(t);
    int c0t = (t & 3) * 64;
    #pragma unroll
    for (int i = 0; i < 8; i++){
      int idx = tid + i*256, r = idx >> 5, g = idx & 31;
      wreg[i] = *(const bf16x8*)(W + (size_t)(c0t + r)*DHID + g*8);
    }
  };
  preload(0);

  for (int t = 0; t < 12; t++){
    __syncthreads();           // prev tile fully read (and Xs ready at t=0)
    #pragma unroll
    for (int i = 0; i < 8; i++){
      int idx = tid + i*256, r = idx >> 5, g = idx & 31;
      *(bf16x8*)(Ws + r*256 + ((g ^ (r & 7))*8)) = wreg[i];
    }
    __syncthreads();
    if (t < 11) preload(t+1);

    f32x4 acc[2][2] = {};
    #pragma unroll
    for (int kk = 0; kk < 8; kk++){
      int off = ((kk*4 + lg) ^ (lr & 7)) * 8;
      bf16x8 a0 = *(const bf16x8*)(Xs + (wr +      lr)*256 + off);
      bf16x8 a1 = *(const bf16x8*)(Xs + (wr + 16 + lr)*256 + off);
      bf16x8 b0 = *(const bf16x8*)(Ws + (wc +      lr)*256 + off);
      bf16x8 b1 = *(const bf16x8*)(Ws + (wc + 16 + lr)*256 + off);
      acc[0][0] = MFMA(a0, b0, acc[0][0]);
      acc[0][1] = MFMA(a0, b1, acc[0][1]);
      acc[1][0] = MFMA(a1, b0, acc[1][0]);
      acc[1][1] = MFMA(a1, b1, acc[1][1]);
    }
    int w = t >> 2, c0t = (t & 3) * 64;
    const uint16_t* bias = (w == 0) ? bq : ((w == 1) ? bk : bv);
    uint16_t* O = (w == 0) ? Oq : ((w == 1) ? Ok : Ov);
    #pragma unroll
    for (int i = 0; i < 2; i++)
    #pragma unroll
    for (int j = 0; j < 2; j++){
      int col = c0t + wc + j*16 + lr;
      float bvv = bf2f(bias[col]);
      #pragma unroll
      for (int rr = 0; rr < 4; rr++){
        int row = r0 + wr + i*16 + lg*4 + rr;
        O[(size_t)row*DHID + col] = f2bf(acc[i][j][rr] + bvv);
      }
    }
  }
}

// ---------------- K2: fused attention per (b,h) ----------------
__global__ __launch_bounds__(256) void k_attn(
    const uint16_t* __restrict__ Q, const uint16_t* __restrict__ Kb, const uint16_t* __restrict__ V,
    const unsigned long long* __restrict__ packed, uint16_t* __restrict__ ctx)
{
  extern __shared__ uint16_t sm[];
  uint16_t* Ks = sm;              // [128][64]  swizzled
  uint16_t* Vt = sm + 128*64;     // [64][128]  V transposed, swizzled
  uint16_t* Ps = Vt + 64*128;     // [128][128] P, swizzled
  const int b = blockIdx.x >> 2;
  const int h = blockIdx.x & 3;
  const int tid = threadIdx.x, lane = tid & 63, wav = tid >> 6;
  const int lr = lane & 15, lg = lane >> 4;
  const size_t base = ((size_t)b * NTOK) * DHID + h * DHEAD;

  #pragma unroll
  for (int i = 0; i < 4; i++){
    int c = tid + i*256;
    int row = c >> 3, g = c & 7;
    *(bf16x8*)(Ks + row*64 + (g ^ (row & 7))*8) =
        *(const bf16x8*)(Kb + base + (size_t)row*DHID + g*8);
  }
  #pragma unroll
  for (int i = 0; i < 4; i++){
    int c = tid + i*256;
    int n = c & 127, d8 = (c >> 7) * 8;
    bf16x8 v = *(const bf16x8*)(V + base + (size_t)n*DHID + d8);
    #pragma unroll
    for (int e = 0; e < 8; e++){
      int d = d8 + e;
      Vt[d*128 + ((n >> 3) ^ (d & 7))*8 + (n & 7)] = (uint16_t)v[e];
    }
  }
  __syncthreads();

  const int qrow0 = wav * 32;
  bf16x8 qf[2][2];
  #pragma unroll
  for (int i = 0; i < 2; i++)
  #pragma unroll
  for (int kk = 0; kk < 2; kk++)
    qf[i][kk] = *(const bf16x8*)(Q + base + (size_t)(qrow0 + i*16 + lr)*DHID + kk*32 + lg*8);

  f32x4 sa[2][8] = {};
  #pragma unroll
  for (int kk = 0; kk < 2; kk++){
    int off = ((kk*4 + lg) ^ (lr & 7)) * 8;
    #pragma unroll
    for (int j = 0; j < 8; j++){
      bf16x8 bf = *(const bf16x8*)(Ks + (j*16 + lr)*64 + off);
      sa[0][j] = MFMA(qf[0][kk], bf, sa[0][j]);
      sa[1][j] = MFMA(qf[1][kk], bf, sa[1][j]);
    }
  }
  #pragma unroll
  for (int i = 0; i < 2; i++){
    #pragma unroll
    for (int rr = 0; rr < 4; rr++){
      int n = qrow0 + i*16 + lg*4 + rr;
      unsigned long long m0 = packed[((size_t)b*NTOK + n)*2 + 0];
      unsigned long long m1 = packed[((size_t)b*NTOK + n)*2 + 1];
      float sv[8];
      float mx = -3.0e38f;
      #pragma unroll
      for (int j = 0; j < 8; j++){
        int col = j*16 + lr;
        unsigned long long w = (col < 64) ? m0 : m1;
        float s = sa[i][j][rr] * 0.125f;
        sv[j] = ((w >> (col & 63)) & 1ull) ? s : -1e9f;
        mx = fmaxf(mx, sv[j]);
      }
      mx = fmaxf(mx, __shfl_xor(mx, 1));
      mx = fmaxf(mx, __shfl_xor(mx, 2));
      mx = fmaxf(mx, __shfl_xor(mx, 4));
      mx = fmaxf(mx, __shfl_xor(mx, 8));
      float sum = 0.f;
      #pragma unroll
      for (int j = 0; j < 8; j++){ sv[j] = __expf(sv[j] - mx); sum += sv[j]; }
      sum += __shfl_xor(sum, 1);
      sum += __shfl_xor(sum, 2);
      sum += __shfl_xor(sum, 4);
      sum += __shfl_xor(sum, 8);
      float inv = 1.f / sum;
      #pragma unroll
      for (int j = 0; j < 8; j++){
        int col = j*16 + lr;
        Ps[n*128 + ((col >> 3) ^ (n & 7))*8 + (col & 7)] = f2bf(sv[j] * inv);
      }
    }
  }
  __syncthreads();

  f32x4 oa[2][4] = {};
  #pragma unroll
  for (int kk = 0; kk < 4; kk++){
    int off = ((kk*4 + lg) ^ (lr & 7)) * 8;
    bf16x8 a0 = *(const bf16x8*)(Ps + (qrow0 +      lr)*128 + off);
    bf16x8 a1 = *(const bf16x8*)(Ps + (qrow0 + 16 + lr)*128 + off);
    #pragma unroll
    for (int j = 0; j < 4; j++){
      bf16x8 bf = *(const bf16x8*)(Vt + (j*16 + lr)*128 + off);
      oa[0][j] = MFMA(a0, bf, oa[0][j]);
      oa[1][j] = MFMA(a1, bf, oa[1][j]);
    }
  }
  #pragma unroll
  for (int i = 0; i < 2; i++)
  #pragma unroll
  for (int j = 0; j < 4; j++)
  #pragma unroll
  for (int rr = 0; rr < 4; rr++){
    int n = qrow0 + i*16 + lg*4 + rr;
    ctx[((size_t)b*NTOK + n)*DHID + h*DHEAD + j*16 + lr] = f2bf(oa[i][j][rr]);
  }
}

// ---------------- K3 v2: fused Wo/GRU with LDS-staged weight slices ----------------
// grid: rows/64; block 256 = 4 waves, wave w owns rows w*16..w*16+15
// LDS: Ls[64][256] (32K) + Cs[64][256] (32K, reused as weight slices) + Is[64][64] (8K) = 72K
__global__ __launch_bounds__(256) void k_gru(
    const uint16_t* __restrict__ ctxp, const uint16_t* __restrict__ lat_in,
    const uint16_t* __restrict__ Wo, const uint16_t* __restrict__ Wih, const uint16_t* __restrict__ Whh,
    const uint16_t* __restrict__ bih, const uint16_t* __restrict__ bhh,
    const unsigned char* __restrict__ upd, uint16_t* __restrict__ lat_out)
{
  extern __shared__ uint16_t sm[];
  uint16_t* Ls = sm;              // [64][256] latent (persists)
  uint16_t* Cs = sm + 64*256;     // [64][256] ctx, then weight slices
  uint16_t* Is = sm + 2*64*256;   // [64][64] info
  uint16_t* WhhS = Cs;            // [48][256] slice
  uint16_t* WihS = Cs + 48*256;   // [48][64]  slice
  const int r0 = blockIdx.x * 64;
  const int tid = threadIdx.x, lane = tid & 63, wav = tid >> 6;
  const int lr = lane & 15, lg = lane >> 4;

  #pragma unroll
  for (int i = 0; i < 8; i++){
    int c = tid + i*256, row = c >> 5, g = c & 31;
    int gs = (g ^ (row & 7)) * 8;
    *(bf16x8*)(Cs + row*256 + gs) = *(const bf16x8*)(ctxp   + (size_t)(r0+row)*DHID + g*8);
    *(bf16x8*)(Ls + row*256 + gs) = *(const bf16x8*)(lat_in + (size_t)(r0+row)*DHID + g*8);
  }
  __syncthreads();

  // phase A: info = ctx @ Wo^T (Wo is 32 KB, L2-resident)
  f32x4 ai[4] = {};
  #pragma unroll
  for (int kk = 0; kk < 8; kk++){
    int off = ((kk*4 + lg) ^ (lr & 7)) * 8;
    bf16x8 a = *(const bf16x8*)(Cs + (wav*16 + lr)*256 + off);
    #pragma unroll
    for (int j = 0; j < 4; j++){
      bf16x8 b = *(const bf16x8*)(Wo + (size_t)(j*16 + lr)*DHID + kk*32 + lg*8);
      ai[j] = MFMA(a, b, ai[j]);
    }
  }
  __syncthreads();
  #pragma unroll
  for (int j = 0; j < 4; j++)
  #pragma unroll
  for (int rr = 0; rr < 4; rr++){
    int row = wav*16 + lg*4 + rr, col = j*16 + lr;
    Is[row*64 + ((col >> 3) ^ (row & 7))*8 + (col & 7)] = f2bf(ai[j][rr]);
  }
  __syncthreads();

  const int wrow = wav*16;
  // cs-invariant A-fragments
  bf16x8 aI[2], aL[8];
  #pragma unroll
  for (int kk = 0; kk < 2; kk++)
    aI[kk] = *(const bf16x8*)(Is + (wrow + lr)*64 + ((kk*4 + lg) ^ (lr & 7))*8);
  #pragma unroll
  for (int kk = 0; kk < 8; kk++)
    aL[kk] = *(const bf16x8*)(Ls + (wrow + lr)*256 + ((kk*4 + lg) ^ (lr & 7))*8);
  unsigned char u4[4];
  #pragma unroll
  for (int rr = 0; rr < 4; rr++) u4[rr] = upd[r0 + wrow + lg*4 + rr];

  bf16x8 wreg[8];
  auto preload = [&](int cs){
    #pragma unroll
    for (int i = 0; i < 8; i++){
      int idx = tid + i*256;
      if (idx < 1536){
        int r = idx >> 5, gc = idx & 31;
        wreg[i] = *(const bf16x8*)(Whh + (size_t)((r >> 4)*256 + cs*16 + (r & 15))*DHID + gc*8);
      } else if (idx < 1920){
        int j2 = idx - 1536, r = j2 >> 3, gc = j2 & 7;
        wreg[i] = *(const bf16x8*)(Wih + (size_t)((r >> 4)*256 + cs*16 + (r & 15))*DHEAD + gc*8);
      }
    }
  };
  preload(0);

  for (int cs = 0; cs < 16; cs++){
    #pragma unroll
    for (int i = 0; i < 8; i++){
      int idx = tid + i*256;
      if (idx < 1536){
        int r = idx >> 5, gc = idx & 31;
        *(bf16x8*)(WhhS + r*256 + ((gc ^ (r & 7))*8)) = wreg[i];
      } else if (idx < 1920){
        int j2 = idx - 1536, r = j2 >> 3, gc = j2 & 7;
        *(bf16x8*)(WihS + r*64 + ((gc ^ (r & 7))*8)) = wreg[i];
      }
    }
    __syncthreads();
    if (cs < 15) preload(cs + 1);

    f32x4 gi[3] = {}, gh[3] = {};
    #pragma unroll
    for (int kk = 0; kk < 2; kk++)
    #pragma unroll
    for (int g = 0; g < 3; g++){
      bf16x8 b = *(const bf16x8*)(WihS + (g*16 + lr)*64 + ((kk*4 + lg) ^ (lr & 7))*8);
      gi[g] = MFMA(aI[kk], b, gi[g]);
    }
    #pragma unroll
    for (int kk = 0; kk < 8; kk++)
    #pragma unroll
    for (int g = 0; g < 3; g++){
      bf16x8 b = *(const bf16x8*)(WhhS + (g*16 + lr)*256 + ((kk*4 + lg) ^ (lr & 7))*8);
      gh[g] = MFMA(aL[kk], b, gh[g]);
    }

    int col = cs*16 + lr;
    float bir = bf2f(bih[col]), biz = bf2f(bih[256+col]), bin_ = bf2f(bih[512+col]);
    float bhr = bf2f(bhh[col]), bhz = bf2f(bhh[256+col]), bhn = bf2f(bhh[512+col]);
    #pragma unroll
    for (int rr = 0; rr < 4; rr++){
      int row = wrow + lg*4 + rr;
      int gcol = (col >> 3) ^ (row & 7);
      float hv = bf2f(Ls[row*256 + gcol*8 + (col & 7)]);
      float rg = 1.f / (1.f + __expf(-((gi[0][rr]+bir) + (gh[0][rr]+bhr))));
      float zg = 1.f / (1.f + __expf(-((gi[1][rr]+biz) + (gh[1][rr]+bhz))));
      float nx = (gi[2][rr]+bin_) + rg*(gh[2][rr]+bhn);
      nx = fminf(20.f, fmaxf(-20.f, nx));
      float e2 = __expf(-2.f * nx);
      float ng = (1.f - e2) / (1.f + e2);
      float hp = (1.f - zg)*ng + zg*hv;
      float ov = u4[rr] ? hp : hv;
      lat_out[(size_t)(r0+row)*DHID + col] = f2bf(ov);
    }
    __syncthreads();
  }
}

extern "C" void kernel_launch(void* const* d_in, const int* in_sizes, int n_in,
                              void* d_out, int out_size, void* d_ws, size_t ws_size,
                              hipStream_t stream)
{
  (void)in_sizes; (void)n_in; (void)out_size;
  const void* latent = d_in[0];
  const int*  mask   = (const int*)d_in[1];
  const void* Wq  = d_in[3]; const void* bq  = d_in[4];
  const void* Wk  = d_in[5]; const void* bk  = d_in[6];
  const void* Wv  = d_in[7]; const void* bv  = d_in[8];
  const void* Wo  = d_in[9];
  const void* Wih = d_in[10]; const void* Whh = d_in[11];
  const void* bih = d_in[12]; const void* bhh = d_in[13];

  uint8_t* p = (uint8_t*)d_ws;
  uint32_t* flag = (uint32_t*)p;            p += 256;
  uint16_t* Wqc  = (uint16_t*)p;            p += 65536*2;
  uint16_t* Wkc  = (uint16_t*)p;            p += 65536*2;
  uint16_t* Wvc  = (uint16_t*)p;            p += 65536*2;
  uint16_t* Woc  = (uint16_t*)p;            p += 16384*2;
  uint16_t* Wihc = (uint16_t*)p;            p += 49152*2;
  uint16_t* Whhc = (uint16_t*)p;            p += 196608*2;
  uint16_t* bqc  = (uint16_t*)p;            p += 512;
  uint16_t* bkc  = (uint16_t*)p;            p += 512;
  uint16_t* bvc  = (uint16_t*)p;            p += 512;
  uint16_t* bihc = (uint16_t*)p;            p += 1536;
  uint16_t* bhhc = (uint16_t*)p;            p += 1536;
  uint8_t* chunk0 = p;
  size_t reserved = (size_t)(chunk0 - (uint8_t*)d_ws);
  const size_t perb = 5ull*65536 + 2048 + 128;

  const int Btot = 1024;
  int CB = (int)((ws_size > reserved ? ws_size - reserved : 0) / perb);
  if (CB > Btot) CB = Btot;
  if (CB < 1)    CB = 1;

  auto cgrid = [](int n){ int b = (n/8 + 255)/256; if (b > 2048) b = 2048; if (b < 1) b = 1; return (unsigned)b; };

  k_detect<<<1, 64, 0, stream>>>((const uint32_t*)latent, flag);
  k_conv<<<cgrid(65536), 256, 0, stream>>>(Wq, 0, Wqc, flag, 65536);
  k_conv<<<cgrid(65536), 256, 0, stream>>>(Wk, 0, Wkc, flag, 65536);
  k_conv<<<cgrid(65536), 256, 0, stream>>>(Wv, 0, Wvc, flag, 65536);
  k_conv<<<cgrid(16384), 256, 0, stream>>>(Wo, 0, Woc, flag, 16384);
  k_conv<<<cgrid(49152), 256, 0, stream>>>(Wih, 0, Wihc, flag, 49152);
  k_conv<<<cgrid(196608),256, 0, stream>>>(Whh, 0, Whhc, flag, 196608);
  k_conv<<<1, 256, 0, stream>>>(bq, 0, bqc, flag, 256);
  k_conv<<<1, 256, 0, stream>>>(bk, 0, bkc, flag, 256);
  k_conv<<<1, 256, 0, stream>>>(bv, 0, bvc, flag, 256);
  k_conv<<<1, 256, 0, stream>>>(bih, 0, bihc, flag, 768);
  k_conv<<<1, 256, 0, stream>>>(bhh, 0, bhhc, flag, 768);

  for (int b0 = 0; b0 < Btot; b0 += CB){
    int cb = (Btot - b0 < CB) ? (Btot - b0) : CB;
    int rows = cb * 128;
    int nelem = rows * DHID;
    uint8_t* q = chunk0;
    uint16_t* L    = (uint16_t*)q; q += (size_t)cb*65536;
    uint16_t* q_ws = (uint16_t*)q; q += (size_t)cb*65536;
    uint16_t* k_ws = (uint16_t*)q; q += (size_t)cb*65536;
    uint16_t* v_ws = (uint16_t*)q; q += (size_t)cb*65536;
    uint16_t* c_ws = (uint16_t*)q; q += (size_t)cb*65536;
    unsigned long long* packed = (unsigned long long*)q; q += (size_t)cb*2048;
    unsigned char* updp = (unsigned char*)q;

    k_conv<<<cgrid(nelem), 256, 0, stream>>>(latent, (unsigned long long)b0*NTOK*DHID, L, flag, nelem);
    k_maskpack<<<dim3(rows/4), 256, 0, stream>>>(mask + (size_t)b0*NTOK*NTOK, packed, updp, rows);

    for (int layer = 0; layer < 2; layer++){
      k_qkv <<<dim3(rows/64),  256, 65536, stream>>>(L, Wqc,bqc, Wkc,bkc, Wvc,bvc, q_ws, k_ws, v_ws);
      k_attn<<<dim3(cb*NHEAD), 256, 65536, stream>>>(q_ws, k_ws, v_ws, packed, c_ws);
      k_gru <<<dim3(rows/64),  256, 73728, stream>>>(c_ws, L, Woc, Wihc, Whhc, bihc, bhhc, updp, L);
    }
    k_store<<<cgrid(nelem), 256, 0, stream>>>(L, d_out, (unsigned long long)b0*NTOK*DHID, flag, nelem);
  }
}

// Round 4
// 766.274 us; speedup vs baseline: 2.2929x; 1.1142x over previous
//
#include <hip/hip_runtime.h>
#include <stdint.h>

#define NTOK 128
#define DHID 256
#define NHEAD 4
#define DHEAD 64

typedef short bf16x8 __attribute__((ext_vector_type(8)));
typedef float f32x4 __attribute__((ext_vector_type(4)));

#define MFMA(a,b,c) __builtin_amdgcn_mfma_f32_16x16x32_bf16((a),(b),(c),0,0,0)

__device__ __forceinline__ float bf2f(uint16_t u){
  union { uint32_t i; float f; } v; v.i = ((uint32_t)u) << 16; return v.f;
}
__device__ __forceinline__ uint16_t f2bf(float f){
  union { uint32_t i; float f; } v; v.f = f;
  uint32_t i = v.i + 0x7FFFu + ((v.i >> 16) & 1u);
  return (uint16_t)(i >> 16);
}

// ---------------- dtype probe ----------------
__global__ void k_detect(const uint32_t* __restrict__ raw, uint32_t* __restrict__ flag){
  int lane = threadIdx.x;
  int hits = 0;
  #pragma unroll
  for (int i = 0; i < 16; i++){
    uint32_t w = raw[lane*16 + i];
    uint32_t e = (w >> 7) & 0xFFu;
    hits += (e >= 0x70u && e <= 0x8Fu) ? 1 : 0;
  }
  #pragma unroll
  for (int m = 1; m < 64; m <<= 1) hits += __shfl_xor(hits, m);
  if (lane == 0) *flag = (hits > 512) ? 1u : 0u;   // 1 = bf16, 0 = fp32
}

// ---------------- normalize float tensor to bf16 ----------------
__global__ void k_conv(const void* __restrict__ src, unsigned long long off,
                       uint16_t* __restrict__ dst, const uint32_t* __restrict__ flag, int n){
  const int isbf = (int)*flag;
  int i0 = (blockIdx.x * blockDim.x + threadIdx.x) * 8;
  int stride = gridDim.x * blockDim.x * 8;
  if (isbf){
    const uint16_t* s = (const uint16_t*)src + off;
    for (int i = i0; i < n; i += stride)
      *(bf16x8*)(dst + i) = *(const bf16x8*)(s + i);
  } else {
    const float* s = (const float*)src + off;
    for (int i = i0; i < n; i += stride){
      float4 a = *(const float4*)(s + i);
      float4 b = *(const float4*)(s + i + 4);
      uint16_t o[8] = {f2bf(a.x),f2bf(a.y),f2bf(a.z),f2bf(a.w),
                       f2bf(b.x),f2bf(b.y),f2bf(b.z),f2bf(b.w)};
      *(bf16x8*)(dst + i) = *(const bf16x8*)o;
    }
  }
}

// ---------------- store result in native dtype ----------------
__global__ void k_store(const uint16_t* __restrict__ L, void* __restrict__ dst,
                        unsigned long long off, const uint32_t* __restrict__ flag, int n){
  const int isbf = (int)*flag;
  int i0 = (blockIdx.x * blockDim.x + threadIdx.x) * 8;
  int stride = gridDim.x * blockDim.x * 8;
  if (isbf){
    uint16_t* d = (uint16_t*)dst + off;
    for (int i = i0; i < n; i += stride)
      *(bf16x8*)(d + i) = *(const bf16x8*)(L + i);
  } else {
    float* d = (float*)dst + off;
    for (int i = i0; i < n; i += stride){
      bf16x8 v = *(const bf16x8*)(L + i);
      #pragma unroll
      for (int e = 0; e < 8; e++) d[i + e] = bf2f((uint16_t)v[e]);
    }
  }
}

// ---------------- K0: pack mask rows ----------------
__global__ __launch_bounds__(256) void k_maskpack(const int* __restrict__ mask,
                                                  unsigned long long* __restrict__ packed,
                                                  unsigned char* __restrict__ upd, int nrows){
  int row = blockIdx.x * 4 + (threadIdx.x >> 6);
  if (row >= nrows) return;
  int lane = threadIdx.x & 63;
  const int* mrow = mask + (size_t)row * NTOK;
  unsigned long long b0 = __ballot(mrow[lane] != 0);
  unsigned long long b1 = __ballot(mrow[lane + 64] != 0);
  if (lane == 0){
    packed[row*2 + 0] = b0;
    packed[row*2 + 1] = b1;
    upd[row] = (unsigned char)((__popcll(b0) + __popcll(b1)) > 1 ? 1 : 0);
  }
}

// ---------------- K1: QKV — stage X once, loop 12 weight tiles ----------------
__global__ __launch_bounds__(256) void k_qkv(
    const uint16_t* __restrict__ X,
    const uint16_t* __restrict__ Wq, const uint16_t* __restrict__ bq,
    const uint16_t* __restrict__ Wk, const uint16_t* __restrict__ bk,
    const uint16_t* __restrict__ Wv, const uint16_t* __restrict__ bv,
    uint16_t* __restrict__ Oq, uint16_t* __restrict__ Ok, uint16_t* __restrict__ Ov)
{
  extern __shared__ uint16_t sm[];
  uint16_t* Xs = sm;            // [64][256] swizzled
  uint16_t* Ws = sm + 64*256;   // [64][256] swizzled (per weight tile)
  const int r0 = blockIdx.x * 64;
  const int tid = threadIdx.x;
  const int lane = tid & 63, lr = lane & 15, lg = lane >> 4;
  const int wav = tid >> 6;
  const int wr = (wav >> 1) * 32, wc = (wav & 1) * 32;

  #pragma unroll
  for (int i = 0; i < 8; i++){
    int c = tid + i*256, row = c >> 5, g = c & 31;
    *(bf16x8*)(Xs + row*256 + (g ^ (row & 7))*8) =
        *(const bf16x8*)(X + (size_t)(r0+row)*DHID + g*8);
  }

  bf16x8 wreg[8];
  auto wptr = [&](int t)->const uint16_t*{
    int w = t >> 2;
    return (w == 0) ? Wq : ((w == 1) ? Wk : Wv);
  };
  auto preload = [&](int t){
    const uint16_t* W = wptr(t);
    int c0t = (t & 3) * 64;
    #pragma unroll
    for (int i = 0; i < 8; i++){
      int idx = tid + i*256, r = idx >> 5, g = idx & 31;
      wreg[i] = *(const bf16x8*)(W + (size_t)(c0t + r)*DHID + g*8);
    }
  };
  preload(0);

  for (int t = 0; t < 12; t++){
    __syncthreads();
    #pragma unroll
    for (int i = 0; i < 8; i++){
      int idx = tid + i*256, r = idx >> 5, g = idx & 31;
      *(bf16x8*)(Ws + r*256 + ((g ^ (r & 7))*8)) = wreg[i];
    }
    __syncthreads();
    if (t < 11) preload(t+1);

    f32x4 acc[2][2] = {};
    #pragma unroll
    for (int kk = 0; kk < 8; kk++){
      int off = ((kk*4 + lg) ^ (lr & 7)) * 8;
      bf16x8 a0 = *(const bf16x8*)(Xs + (wr +      lr)*256 + off);
      bf16x8 a1 = *(const bf16x8*)(Xs + (wr + 16 + lr)*256 + off);
      bf16x8 b0 = *(const bf16x8*)(Ws + (wc +      lr)*256 + off);
      bf16x8 b1 = *(const bf16x8*)(Ws + (wc + 16 + lr)*256 + off);
      acc[0][0] = MFMA(a0, b0, acc[0][0]);
      acc[0][1] = MFMA(a0, b1, acc[0][1]);
      acc[1][0] = MFMA(a1, b0, acc[1][0]);
      acc[1][1] = MFMA(a1, b1, acc[1][1]);
    }
    int w = t >> 2, c0t = (t & 3) * 64;
    const uint16_t* bias = (w == 0) ? bq : ((w == 1) ? bk : bv);
    uint16_t* O = (w == 0) ? Oq : ((w == 1) ? Ok : Ov);
    #pragma unroll
    for (int i = 0; i < 2; i++)
    #pragma unroll
    for (int j = 0; j < 2; j++){
      int col = c0t + wc + j*16 + lr;
      float bvv = bf2f(bias[col]);
      #pragma unroll
      for (int rr = 0; rr < 4; rr++){
        int row = r0 + wr + i*16 + lg*4 + rr;
        O[(size_t)row*DHID + col] = f2bf(acc[i][j][rr] + bvv);
      }
    }
  }
}

// ---------------- K2: fused attention per (b,h) ----------------
__global__ __launch_bounds__(256) void k_attn(
    const uint16_t* __restrict__ Q, const uint16_t* __restrict__ Kb, const uint16_t* __restrict__ V,
    const unsigned long long* __restrict__ packed, uint16_t* __restrict__ ctx)
{
  extern __shared__ uint16_t sm[];
  uint16_t* Ks = sm;              // [128][64]  swizzled
  uint16_t* Vt = sm + 128*64;     // [64][128]  V transposed, swizzled
  uint16_t* Ps = Vt + 64*128;     // [128][128] P, swizzled
  const int b = blockIdx.x >> 2;
  const int h = blockIdx.x & 3;
  const int tid = threadIdx.x, lane = tid & 63, wav = tid >> 6;
  const int lr = lane & 15, lg = lane >> 4;
  const size_t base = ((size_t)b * NTOK) * DHID + h * DHEAD;

  #pragma unroll
  for (int i = 0; i < 4; i++){
    int c = tid + i*256;
    int row = c >> 3, g = c & 7;
    *(bf16x8*)(Ks + row*64 + (g ^ (row & 7))*8) =
        *(const bf16x8*)(Kb + base + (size_t)row*DHID + g*8);
  }
  #pragma unroll
  for (int i = 0; i < 4; i++){
    int c = tid + i*256;
    int n = c & 127, d8 = (c >> 7) * 8;
    bf16x8 v = *(const bf16x8*)(V + base + (size_t)n*DHID + d8);
    #pragma unroll
    for (int e = 0; e < 8; e++){
      int d = d8 + e;
      Vt[d*128 + ((n >> 3) ^ (d & 7))*8 + (n & 7)] = (uint16_t)v[e];
    }
  }
  __syncthreads();

  const int qrow0 = wav * 32;
  bf16x8 qf[2][2];
  #pragma unroll
  for (int i = 0; i < 2; i++)
  #pragma unroll
  for (int kk = 0; kk < 2; kk++)
    qf[i][kk] = *(const bf16x8*)(Q + base + (size_t)(qrow0 + i*16 + lr)*DHID + kk*32 + lg*8);

  f32x4 sa[2][8] = {};
  #pragma unroll
  for (int kk = 0; kk < 2; kk++){
    int off = ((kk*4 + lg) ^ (lr & 7)) * 8;
    #pragma unroll
    for (int j = 0; j < 8; j++){
      bf16x8 bf = *(const bf16x8*)(Ks + (j*16 + lr)*64 + off);
      sa[0][j] = MFMA(qf[0][kk], bf, sa[0][j]);
      sa[1][j] = MFMA(qf[1][kk], bf, sa[1][j]);
    }
  }
  #pragma unroll
  for (int i = 0; i < 2; i++){
    #pragma unroll
    for (int rr = 0; rr < 4; rr++){
      int n = qrow0 + i*16 + lg*4 + rr;
      unsigned long long m0 = packed[((size_t)b*NTOK + n)*2 + 0];
      unsigned long long m1 = packed[((size_t)b*NTOK + n)*2 + 1];
      float sv[8];
      float mx = -3.0e38f;
      #pragma unroll
      for (int j = 0; j < 8; j++){
        int col = j*16 + lr;
        unsigned long long w = (col < 64) ? m0 : m1;
        float s = sa[i][j][rr] * 0.125f;
        sv[j] = ((w >> (col & 63)) & 1ull) ? s : -1e9f;
        mx = fmaxf(mx, sv[j]);
      }
      mx = fmaxf(mx, __shfl_xor(mx, 1));
      mx = fmaxf(mx, __shfl_xor(mx, 2));
      mx = fmaxf(mx, __shfl_xor(mx, 4));
      mx = fmaxf(mx, __shfl_xor(mx, 8));
      float sum = 0.f;
      #pragma unroll
      for (int j = 0; j < 8; j++){ sv[j] = __expf(sv[j] - mx); sum += sv[j]; }
      sum += __shfl_xor(sum, 1);
      sum += __shfl_xor(sum, 2);
      sum += __shfl_xor(sum, 4);
      sum += __shfl_xor(sum, 8);
      float inv = __builtin_amdgcn_rcpf(sum);
      #pragma unroll
      for (int j = 0; j < 8; j++){
        int col = j*16 + lr;
        Ps[n*128 + ((col >> 3) ^ (n & 7))*8 + (col & 7)] = f2bf(sv[j] * inv);
      }
    }
  }
  __syncthreads();

  f32x4 oa[2][4] = {};
  #pragma unroll
  for (int kk = 0; kk < 4; kk++){
    int off = ((kk*4 + lg) ^ (lr & 7)) * 8;
    bf16x8 a0 = *(const bf16x8*)(Ps + (qrow0 +      lr)*128 + off);
    bf16x8 a1 = *(const bf16x8*)(Ps + (qrow0 + 16 + lr)*128 + off);
    #pragma unroll
    for (int j = 0; j < 4; j++){
      bf16x8 bf = *(const bf16x8*)(Vt + (j*16 + lr)*128 + off);
      oa[0][j] = MFMA(a0, bf, oa[0][j]);
      oa[1][j] = MFMA(a1, bf, oa[1][j]);
    }
  }
  #pragma unroll
  for (int i = 0; i < 2; i++)
  #pragma unroll
  for (int j = 0; j < 4; j++)
  #pragma unroll
  for (int rr = 0; rr < 4; rr++){
    int n = qrow0 + i*16 + lg*4 + rr;
    ctx[((size_t)b*NTOK + n)*DHID + h*DHEAD + j*16 + lr] = f2bf(oa[i][j][rr]);
  }
}

// ---------------- K3 v3: fused Wo/GRU, 128 rows/block, 8 waves ----------------
// A-fragments direct from global (L2-hot); only weight slices + info + bias in LDS.
// LDS: WhhS[48][256] 24K + WihS[48][64] 6K + Is[128][64] 16K + biasS[1536] 3K = 50176 B
__global__ __launch_bounds__(512, 4) void k_gru(
    const uint16_t* __restrict__ ctxp, const uint16_t* __restrict__ lat,
    const uint16_t* __restrict__ Wo, const uint16_t* __restrict__ Wih, const uint16_t* __restrict__ Whh,
    const uint16_t* __restrict__ bih, const uint16_t* __restrict__ bhh,
    const unsigned char* __restrict__ upd, uint16_t* __restrict__ lat_out)
{
  extern __shared__ uint16_t sm[];
  uint16_t* WhhS  = sm;            // [48][256] swizzled
  uint16_t* WihS  = sm + 12288;    // [48][64]  swizzled
  uint16_t* Is    = sm + 15360;    // [128][64] swizzled
  uint16_t* biasS = sm + 23552;    // [1536]
  const int r0 = blockIdx.x * 128;
  const int tid = threadIdx.x, lane = tid & 63, wav = tid >> 6;
  const int lr = lane & 15, lg = lane >> 4;
  const int wrow = wav * 16;

  #pragma unroll
  for (int i = 0; i < 3; i++){
    int idx = tid + i*512;
    if (idx < 1536) biasS[idx] = (idx < 768) ? bih[idx] : bhh[idx - 768];
  }

  bf16x8 wreg[4];
  auto preload = [&](int cs){
    #pragma unroll
    for (int i = 0; i < 4; i++){
      int idx = tid + i*512;
      if (idx < 1536){
        int r = idx >> 5, gc = idx & 31;
        wreg[i] = *(const bf16x8*)(Whh + (size_t)((r>>4)*256 + cs*16 + (r&15))*DHID + gc*8);
      } else if (idx < 1920){
        int j2 = idx - 1536, r = j2 >> 3, gc = j2 & 7;
        wreg[i] = *(const bf16x8*)(Wih + (size_t)((r>>4)*256 + cs*16 + (r&15))*DHEAD + gc*8);
      }
    }
  };
  auto stagew = [&](){
    #pragma unroll
    for (int i = 0; i < 4; i++){
      int idx = tid + i*512;
      if (idx < 1536){
        int r = idx >> 5, gc = idx & 31;
        *(bf16x8*)(WhhS + r*256 + ((gc ^ (r&7))*8)) = wreg[i];
      } else if (idx < 1920){
        int j2 = idx - 1536, r = j2 >> 3, gc = j2 & 7;
        *(bf16x8*)(WihS + r*64 + ((gc ^ (r&7))*8)) = wreg[i];
      }
    }
  };
  preload(0);

  // cs-invariant A-fragments, direct from global
  bf16x8 aL[8], actx[8];
  #pragma unroll
  for (int kk = 0; kk < 8; kk++){
    size_t rowb = (size_t)(r0 + wrow + lr);
    aL[kk]   = *(const bf16x8*)(lat  + rowb*DHID + kk*32 + lg*8);
    actx[kk] = *(const bf16x8*)(ctxp + rowb*DHID + kk*32 + lg*8);
  }
  uint32_t u4;
  {
    const unsigned char* up = upd + r0 + wrow + lg*4;
    u4 = (uint32_t)up[0] | ((uint32_t)up[1]<<8) | ((uint32_t)up[2]<<16) | ((uint32_t)up[3]<<24);
  }

  // phase A: info = ctx @ Wo^T (Wo B-fragments direct from global, L2-resident)
  f32x4 ai[4] = {};
  #pragma unroll
  for (int kk = 0; kk < 8; kk++){
    #pragma unroll
    for (int j = 0; j < 4; j++){
      bf16x8 b = *(const bf16x8*)(Wo + (size_t)(j*16 + lr)*DHID + kk*32 + lg*8);
      ai[j] = MFMA(actx[kk], b, ai[j]);
    }
  }
  #pragma unroll
  for (int j = 0; j < 4; j++)
  #pragma unroll
  for (int rr = 0; rr < 4; rr++){
    int row = wrow + lg*4 + rr, col = j*16 + lr;
    Is[row*64 + ((col>>3) ^ (row&7))*8 + (col&7)] = f2bf(ai[j][rr]);
  }
  stagew();
  __syncthreads();

  bf16x8 aI[2];
  #pragma unroll
  for (int kk = 0; kk < 2; kk++)
    aI[kk] = *(const bf16x8*)(Is + (wrow + lr)*64 + ((kk*4 + lg) ^ (lr&7))*8);

  const float LOG2E = 1.44269504f;
  for (int cs = 0; cs < 16; cs++){
    if (cs < 15) preload(cs+1);
    f32x4 gi[3] = {}, gh[3] = {};
    #pragma unroll
    for (int kk = 0; kk < 2; kk++)
    #pragma unroll
    for (int g = 0; g < 3; g++){
      bf16x8 b = *(const bf16x8*)(WihS + (g*16+lr)*64 + ((kk*4+lg)^(lr&7))*8);
      gi[g] = MFMA(aI[kk], b, gi[g]);
    }
    #pragma unroll
    for (int kk = 0; kk < 8; kk++)
    #pragma unroll
    for (int g = 0; g < 3; g++){
      bf16x8 b = *(const bf16x8*)(WhhS + (g*16+lr)*256 + ((kk*4+lg)^(lr&7))*8);
      gh[g] = MFMA(aL[kk], b, gh[g]);
    }
    int col = cs*16 + lr;
    float bir = bf2f(biasS[col]),     biz = bf2f(biasS[256+col]),  bin_ = bf2f(biasS[512+col]);
    float bhr = bf2f(biasS[768+col]), bhz = bf2f(biasS[1024+col]), bhn  = bf2f(biasS[1280+col]);
    #pragma unroll
    for (int rr = 0; rr < 4; rr++){
      int row = wrow + lg*4 + rr;
      float hv = bf2f(lat[(size_t)(r0+row)*DHID + col]);
      float xr = (gi[0][rr]+bir) + (gh[0][rr]+bhr);
      float xz = (gi[1][rr]+biz) + (gh[1][rr]+bhz);
      float rg = __builtin_amdgcn_rcpf(1.f + __builtin_amdgcn_exp2f(-xr*LOG2E));
      float zg = __builtin_amdgcn_rcpf(1.f + __builtin_amdgcn_exp2f(-xz*LOG2E));
      float nx = (gi[2][rr]+bin_) + rg*(gh[2][rr]+bhn);
      nx = fminf(10.f, fmaxf(-10.f, nx));
      float e2 = __builtin_amdgcn_exp2f(-2.f*LOG2E*nx);
      float ng = (1.f - e2) * __builtin_amdgcn_rcpf(1.f + e2);
      float hp = (1.f - zg)*ng + zg*hv;
      float ov = ((u4 >> (rr*8)) & 1u) ? hp : hv;
      lat_out[(size_t)(r0+row)*DHID + col] = f2bf(ov);
    }
    __syncthreads();               // all waves done reading slice cs
    if (cs < 15){ stagew(); __syncthreads(); }
  }
}

extern "C" void kernel_launch(void* const* d_in, const int* in_sizes, int n_in,
                              void* d_out, int out_size, void* d_ws, size_t ws_size,
                              hipStream_t stream)
{
  (void)in_sizes; (void)n_in; (void)out_size;
  const void* latent = d_in[0];
  const int*  mask   = (const int*)d_in[1];
  const void* Wq  = d_in[3]; const void* bq  = d_in[4];
  const void* Wk  = d_in[5]; const void* bk  = d_in[6];
  const void* Wv  = d_in[7]; const void* bv  = d_in[8];
  const void* Wo  = d_in[9];
  const void* Wih = d_in[10]; const void* Whh = d_in[11];
  const void* bih = d_in[12]; const void* bhh = d_in[13];

  uint8_t* p = (uint8_t*)d_ws;
  uint32_t* flag = (uint32_t*)p;            p += 256;
  uint16_t* Wqc  = (uint16_t*)p;            p += 65536*2;
  uint16_t* Wkc  = (uint16_t*)p;            p += 65536*2;
  uint16_t* Wvc  = (uint16_t*)p;            p += 65536*2;
  uint16_t* Woc  = (uint16_t*)p;            p += 16384*2;
  uint16_t* Wihc = (uint16_t*)p;            p += 49152*2;
  uint16_t* Whhc = (uint16_t*)p;            p += 196608*2;
  uint16_t* bqc  = (uint16_t*)p;            p += 512;
  uint16_t* bkc  = (uint16_t*)p;            p += 512;
  uint16_t* bvc  = (uint16_t*)p;            p += 512;
  uint16_t* bihc = (uint16_t*)p;            p += 1536;
  uint16_t* bhhc = (uint16_t*)p;            p += 1536;
  uint8_t* chunk0 = p;
  size_t reserved = (size_t)(chunk0 - (uint8_t*)d_ws);
  const size_t perb = 5ull*65536 + 2048 + 128;

  const int Btot = 1024;
  int CB = (int)((ws_size > reserved ? ws_size - reserved : 0) / perb);
  if (CB > Btot) CB = Btot;
  if (CB < 1)    CB = 1;

  auto cgrid = [](int n){ int b = (n/8 + 255)/256; if (b > 2048) b = 2048; if (b < 1) b = 1; return (unsigned)b; };

  k_detect<<<1, 64, 0, stream>>>((const uint32_t*)latent, flag);
  k_conv<<<cgrid(65536), 256, 0, stream>>>(Wq, 0, Wqc, flag, 65536);
  k_conv<<<cgrid(65536), 256, 0, stream>>>(Wk, 0, Wkc, flag, 65536);
  k_conv<<<cgrid(65536), 256, 0, stream>>>(Wv, 0, Wvc, flag, 65536);
  k_conv<<<cgrid(16384), 256, 0, stream>>>(Wo, 0, Woc, flag, 16384);
  k_conv<<<cgrid(49152), 256, 0, stream>>>(Wih, 0, Wihc, flag, 49152);
  k_conv<<<cgrid(196608),256, 0, stream>>>(Whh, 0, Whhc, flag, 196608);
  k_conv<<<1, 256, 0, stream>>>(bq, 0, bqc, flag, 256);
  k_conv<<<1, 256, 0, stream>>>(bk, 0, bkc, flag, 256);
  k_conv<<<1, 256, 0, stream>>>(bv, 0, bvc, flag, 256);
  k_conv<<<1, 256, 0, stream>>>(bih, 0, bihc, flag, 768);
  k_conv<<<1, 256, 0, stream>>>(bhh, 0, bhhc, flag, 768);

  for (int b0 = 0; b0 < Btot; b0 += CB){
    int cb = (Btot - b0 < CB) ? (Btot - b0) : CB;
    int rows = cb * 128;
    int nelem = rows * DHID;
    uint8_t* q = chunk0;
    uint16_t* L    = (uint16_t*)q; q += (size_t)cb*65536;
    uint16_t* q_ws = (uint16_t*)q; q += (size_t)cb*65536;
    uint16_t* k_ws = (uint16_t*)q; q += (size_t)cb*65536;
    uint16_t* v_ws = (uint16_t*)q; q += (size_t)cb*65536;
    uint16_t* c_ws = (uint16_t*)q; q += (size_t)cb*65536;
    unsigned long long* packed = (unsigned long long*)q; q += (size_t)cb*2048;
    unsigned char* updp = (unsigned char*)q;

    k_conv<<<cgrid(nelem), 256, 0, stream>>>(latent, (unsigned long long)b0*NTOK*DHID, L, flag, nelem);
    k_maskpack<<<dim3(rows/4), 256, 0, stream>>>(mask + (size_t)b0*NTOK*NTOK, packed, updp, rows);

    for (int layer = 0; layer < 2; layer++){
      k_qkv <<<dim3(rows/64),  256, 65536, stream>>>(L, Wqc,bqc, Wkc,bkc, Wvc,bvc, q_ws, k_ws, v_ws);
      k_attn<<<dim3(cb*NHEAD), 256, 65536, stream>>>(q_ws, k_ws, v_ws, packed, c_ws);
      k_gru <<<dim3(rows/128), 512, 50176, stream>>>(c_ws, L, Woc, Wihc, Whhc, bihc, bhhc, updp, L);
    }
    k_store<<<cgrid(nelem), 256, 0, stream>>>(L, d_out, (unsigned long long)b0*NTOK*DHID, flag, nelem);
  }
}